// Round 8
// baseline (358.185 us; speedup 1.0000x reference)
//
#include <hip/hip_runtime.h>
#include <hip/hip_bf16.h>
#include <hip/hip_fp16.h>
#include <math.h>

// ROUND 15: conflict-free GEMM LDS (interleaved A|W 128B rows, per-lane DMA
// source) + T14 async-stage attn + wo split-K=4.
// r14 evidence: QKVG gemm16 94us top (MfmaUtil 31, Occ 34.5, HBM 11.5,
// BANK_CONFLICT 8.4M=2^23). 64B LDS rows gave the frag read only 2 XOR bits
// (q^(l15&3)) -> 16 lanes on 4 bank-groups = 4-way conflict (1.58x, m136).
// Fix: one sAW[2][128][64] array, row = [A granules | W granules], phys
// granule = logical ^ (row&7); global_load_lds dest stays linear, per-lane
// SOURCE picks A or W (lg=(l&7)^(l>>3)) -> reads 2-way (free), writes linear.
// attn: issue next tile's K/V reg-loads before current tile's QK/PV (T14);
// analytic jstart replaces in-loop decay skip. wo: split-K=4, fp16 partials.
// Established: inputs fp32, output fp32 (ref bf16-quantized), ws >= 96 MiB.
// ws MiB: 0 x16/part0 |8 wq16/part1 |16 wk16/part2 |24 wv16/part3 |32 wg16
// |40 wo16 |48 q16/wp0 |56 k16/wp1 |64 vt/wp2 |72 p0/wp3 |88 a16.
// g fp16 staged in d_out[0,8M), dead before addk4 overwrites d_out fp32.

typedef _Float16 hlf;
typedef unsigned short u16;
typedef __attribute__((ext_vector_type(4))) float f32x4;
typedef __attribute__((ext_vector_type(8))) _Float16 hlf8;
typedef __attribute__((ext_vector_type(4))) _Float16 hlf4;

#define S_ 2048
#define D_ 2048
#define H_ 16
#define HD_ 128
#define SCALE_ 0.08838834764831843f   // 128^-0.5

__device__ __forceinline__ bool is_f32(const void* p) {
  const u16* xr = (const u16*)p;
  int cnt = 0;
  for (int i = 0; i < 128; ++i) {
    int e = (xr[2 * i] >> 7) & 0xFF;
    cnt += (e >= 100 && e <= 140) ? 1 : 0;
  }
  return cnt < 96;
}

__device__ __forceinline__ void gl16(const void* g, void* l) {
  __builtin_amdgcn_global_load_lds(
      (const __attribute__((address_space(1))) void*)g,
      (__attribute__((address_space(3))) void*)l, 16, 0, 0);
}

// ---------------------------------------------------------------------------
// cvt16: fp32 -> fp16 bulk convert, 6 segments of 4M floats.
// ---------------------------------------------------------------------------
__global__ __launch_bounds__(256) void cvt16(
    const float* __restrict__ s0, const float* __restrict__ s1,
    const float* __restrict__ s2, const float* __restrict__ s3,
    const float* __restrict__ s4, const float* __restrict__ s5,
    hlf* __restrict__ d0, hlf* __restrict__ d1, hlf* __restrict__ d2,
    hlf* __restrict__ d3, hlf* __restrict__ d4, hlf* __restrict__ d5) {
  const int seg = blockIdx.y;
  const float* s = (seg == 0) ? s0 : (seg == 1) ? s1 : (seg == 2) ? s2
                 : (seg == 3) ? s3 : (seg == 4) ? s4 : s5;
  hlf* d = (seg == 0) ? d0 : (seg == 1) ? d1 : (seg == 2) ? d2
         : (seg == 3) ? d3 : (seg == 4) ? d4 : d5;
#pragma unroll
  for (int n = 0; n < 4; ++n) {
    size_t ci = (size_t)blockIdx.x * 1024 + n * 256 + threadIdx.x;
    f32x4 v = *(const f32x4*)(s + ci * 4);
    hlf4 o;
#pragma unroll
    for (int e = 0; e < 4; ++e) o[e] = (hlf)v[e];
    *(hlf4*)(d + ci * 4) = o;
  }
}

// ---------------------------------------------------------------------------
// gemm16: C = A @ W^T, fp16 in, 128x128 tile, BK=32, DMA staging into
// interleaved sAW[2][128][64]: row r = [A(r0+r) | W(c0+r)], phys granule =
// logical ^ (r&7). Per-lane DMA source picks A/W + chunk; dest linear.
// k0z*z = split-K offset; nkt = K-steps. mode: 1=fp16 out, 2=trans, 4=silu.
// ---------------------------------------------------------------------------
__global__ __launch_bounds__(256, 4) void gemm16(
    const hlf* __restrict__ A,
    const hlf* __restrict__ W0, const hlf* __restrict__ W1,
    const hlf* __restrict__ W2, const hlf* __restrict__ W3,
    void* __restrict__ C0, void* __restrict__ C1,
    void* __restrict__ C2, void* __restrict__ C3, int modes,
    int k0z, int nkt) {
  __shared__ __align__(16) hlf sAW[2][128][64];

  const int z = blockIdx.z;
  const hlf* W = (z == 0) ? W0 : (z == 1) ? W1 : (z == 2) ? W2 : W3;
  void* Cv     = (z == 0) ? C0 : (z == 1) ? C1 : (z == 2) ? C2 : C3;
  const int mode = (modes >> (4 * z)) & 15;
  const int k0 = k0z * z;

  const int t = threadIdx.x;
  const int lane = t & 63;
  const int wv = t >> 6;
  const int wr = (wv >> 1) * 64;
  const int wc = (wv & 1) * 64;
  const int r0 = blockIdx.y * 128;
  const int c0 = blockIdx.x * 128;

  const int l15 = lane & 15;
  const int q = lane >> 4;                   // frag k-chunk 0..3
  const int ga = (q ^ (l15 & 7)) * 8;        // A frag phys offset (halfs)
  const int gw = ((q | 4) ^ (l15 & 7)) * 8;  // W frag phys offset

  // DMA source mapping: instr u (0..3) of wave wv covers LDS rows
  // 32*wv + u*8 + (lane>>3), phys granule lane&7. Logical granule
  // lg = (lane&7) ^ (lane>>3); lg<4 -> A chunk lg, else W chunk lg&3.
  const int rsub = lane >> 3;                // 0..7
  const int lg = (lane & 7) ^ rsub;
  const int ch = lg & 3;
  const hlf* srcbase =
      ((lg < 4) ? A + (size_t)(r0 + 32 * wv + rsub) * D_
                : W + (size_t)(c0 + 32 * wv + rsub) * D_) + k0 + ch * 8;

  hlf* const awflat = &sAW[0][0][0];
  const int BUF = 128 * 64;                  // halfs per buffer

  f32x4 acc[4][4];
#pragma unroll
  for (int i = 0; i < 4; ++i)
#pragma unroll
    for (int j = 0; j < 4; ++j) acc[i][j] = (f32x4){0.f, 0.f, 0.f, 0.f};

  auto stage = [&](int kt, int buf) {
    const int ko = kt * 32;
    hlf* ld = awflat + buf * BUF + wv * 2048;
#pragma unroll
    for (int u = 0; u < 4; ++u)
      gl16(srcbase + ko + u * 8 * D_, ld + u * 512);
  };

  stage(0, 0);
  __syncthreads();

  for (int kt = 0; kt < nkt; ++kt) {
    const int cur = kt & 1;
    if (kt + 1 < nkt) stage(kt + 1, cur ^ 1);

    hlf8 fa[4], fw[4];
#pragma unroll
    for (int i = 0; i < 4; ++i) {
      fa[i] = *(const hlf8*)&sAW[cur][wr + i * 16 + l15][ga];
      fw[i] = *(const hlf8*)&sAW[cur][wc + i * 16 + l15][gw];
    }
#pragma unroll
    for (int i = 0; i < 4; ++i)
#pragma unroll
      for (int j = 0; j < 4; ++j)
        acc[i][j] = __builtin_amdgcn_mfma_f32_16x16x32_f16(fa[i], fw[j], acc[i][j], 0, 0, 0);

    __syncthreads();
  }

  const int orow = (lane >> 4) * 4;   // C/D: col=lane&15, row=(lane>>4)*4+r
  if (mode & 2) {                      // transposed fp16 vT[n][s]
#pragma unroll
    for (int i = 0; i < 4; ++i)
#pragma unroll
      for (int j = 0; j < 4; ++j) {
        hlf4 p;
#pragma unroll
        for (int r = 0; r < 4; ++r) p[r] = (hlf)acc[i][j][r];
        size_t n  = (size_t)(c0 + wc + j * 16 + l15);
        size_t s0 = (size_t)(r0 + wr + i * 16 + orow);
        *(hlf4*)((hlf*)Cv + n * (size_t)S_ + s0) = p;
      }
  } else {
#pragma unroll
    for (int i = 0; i < 4; ++i)
#pragma unroll
      for (int j = 0; j < 4; ++j)
#pragma unroll
        for (int r = 0; r < 4; ++r) {
          float val = acc[i][j][r];
          if (mode & 4) val = val / (1.f + expf(-val));
          size_t idx = (size_t)(r0 + wr + i * 16 + orow + r) * D_ +
                       (c0 + wc + j * 16 + l15);
          if (mode & 1) ((hlf*)Cv)[idx] = (hlf)val;
          else          ((float*)Cv)[idx] = val;
        }
  }
}

// ---------------------------------------------------------------------------
// attn_part: retention attention, j-chunked partial sums, T14 async staging.
// Block = (head, i-tile bx, chunk c); j-tiles [8c, min(8c+8,bx+1)).
// ---------------------------------------------------------------------------
__global__ __launch_bounds__(256, 4) void attn_part(
    const hlf* __restrict__ q16, const hlf* __restrict__ k16,
    const hlf* __restrict__ vt, hlf* __restrict__ part) {
  const int h = blockIdx.y;
  const int f = blockIdx.x;          // 0..79
  int bx, c;
  if (f < 8)       { bx = f; c = 0; }
  else if (f < 24) { bx = 8 + ((f - 8) >> 1); c = (f - 8) & 1; }
  else if (f < 48) { int u = f - 24; int q3 = u / 3; bx = 16 + q3; c = u - q3 * 3; }
  else             { int u = f - 48; bx = 24 + (u >> 2); c = u & 3; }

  const int i0 = bx * 64;
  const int jlo = c * 8;
  const int jhi = min(jlo + 8, bx + 1);

  const int t = threadIdx.x;
  const int lane = t & 63;
  const int wv = t >> 6;
  const int l15 = lane & 15;
  const int hi = lane >> 4;

  __shared__ __align__(16) hlf skh[64][128];   // k, granule swz ^(row&15)
  __shared__ __align__(16) hlf svt[128][64];   // vT, granule swz ^(d&7)
  __shared__ __align__(16) hlf ssc[4][16][64]; // scores per wave

  const double l1 = -3.4657359027997265;
  const double l2 = -6.238324625039508;
  const float gam = (float)(1.0 - exp(l1 + (double)h * ((l2 - l1) / 15.0)));
  const float log2g = log2f(gam);

  // q frags: A layout row=lane&15, k=(lane>>4)*8+e; scaled SCALE*gamma^(i-i0)
  hlf8 fq[4];
  {
    const float qs = SCALE_ * exp2f((float)(wv * 16 + l15) * log2g);
    const hlf* qrow = q16 + (size_t)(i0 + wv * 16 + l15) * D_ + h * HD_;
#pragma unroll
    for (int ks = 0; ks < 4; ++ks) {
      hlf8 v = *(const hlf8*)(qrow + ks * 32 + hi * 8);
      hlf8 hh;
#pragma unroll
      for (int e = 0; e < 8; ++e) hh[e] = (hlf)((float)v[e] * qs);
      fq[ks] = hh;
    }
  }

  // staging index precompute (per-thread constants)
  int krow[4], kg[4], vd[4], vg[4];
  float rsc[4];
#pragma unroll
  for (int n = 0; n < 4; ++n) {
    int id = t + 256 * n;
    krow[n] = id >> 4;                 // 0..63
    kg[n] = id & 15;
    vd[n] = id >> 3;                   // 0..127
    vg[n] = id & 7;
    rsc[n] = exp2f(-(float)krow[n] * log2g);
  }

  hlf8 kreg[4], vreg[4];
  auto LOAD = [&](int jt) {
    const int j0 = jt * 64;
#pragma unroll
    for (int n = 0; n < 4; ++n)
      kreg[n] = *(const hlf8*)(k16 + (size_t)(j0 + krow[n]) * D_ + h * HD_ + kg[n] * 8);
#pragma unroll
    for (int n = 0; n < 4; ++n)
      vreg[n] = *(const hlf8*)(vt + (size_t)(h * HD_ + vd[n]) * S_ + j0 + vg[n] * 8);
  };
  auto STAGE = [&](int jt) {
    const float tsc = exp2f((float)(i0 - jt * 64) * log2g);
#pragma unroll
    for (int n = 0; n < 4; ++n) {
      float ksc = tsc * rsc[n];
      hlf8 hh;
#pragma unroll
      for (int e = 0; e < 8; ++e) hh[e] = (hlf)((float)kreg[n][e] * ksc);
      *(hlf8*)&skh[krow[n]][(kg[n] ^ (krow[n] & 15)) << 3] = hh;
    }
#pragma unroll
    for (int n = 0; n < 4; ++n)
      *(hlf8*)&svt[vd[n]][(vg[n] ^ (vd[n] & 7)) << 3] = vreg[n];
  };

  f32x4 yacc[8];
#pragma unroll
  for (int dt = 0; dt < 8; ++dt) yacc[dt] = (f32x4){0.f, 0.f, 0.f, 0.f};

  // decay skip: analytic first live tile (whole-tile factor >= 2^-20)
  int jstart = jlo;
  while (jstart < jhi && (float)(i0 - jstart * 64 - 63) * log2g < -20.0f)
    ++jstart;

  if (jstart < jhi) LOAD(jstart);
  for (int jt = jstart; jt < jhi; ++jt) {
    __syncthreads();                 // prev frag reads done before restage
    STAGE(jt);                       // consumes kreg/vreg
    if (jt + 1 < jhi) LOAD(jt + 1);  // issue early; hides under QK/PV
    __syncthreads();

    const bool diag = (jt == bx);

    // QK^T: per wave 16x64 scores
#pragma unroll
    for (int jf = 0; jf < 4; ++jf) {
      f32x4 s = (f32x4){0.f, 0.f, 0.f, 0.f};
#pragma unroll
      for (int ks = 0; ks < 4; ++ks) {
        int kr = jf * 16 + l15;
        int sw = (((ks * 4 + hi) ^ (kr & 15)) << 3);
        hlf8 kb = *(const hlf8*)&skh[kr][sw];
        s = __builtin_amdgcn_mfma_f32_16x16x32_f16(fq[ks], kb, s, 0, 0, 0);
      }
#pragma unroll
      for (int r = 0; r < 4; ++r) {
        float val = s[r];
        int il = hi * 4 + r;
        int jl = jf * 16 + l15;
        if (diag && (wv * 16 + il) < jl) val = 0.f;
        int swc = (((jl >> 3) ^ (il & 7)) << 3) + (jl & 7);
        ssc[wv][il][swc] = (hlf)val;
      }
    }

    // PV: yacc[dt] += scores(16x64) @ vT-tile(64x128)
#pragma unroll
    for (int ks = 0; ks < 2; ++ks) {
      int gA = ks * 4 + hi;
      hlf8 sa = *(const hlf8*)&ssc[wv][l15][(gA ^ (l15 & 7)) << 3];
#pragma unroll
      for (int dt = 0; dt < 8; ++dt) {
        int d = dt * 16 + l15;
        hlf8 vb = *(const hlf8*)&svt[d][(gA ^ (d & 7)) << 3];
        yacc[dt] = __builtin_amdgcn_mfma_f32_16x16x32_f16(sa, vb, yacc[dt], 0, 0, 0);
      }
    }
  }

  // epilogue: fp16 partial; D col=l15 -> d, row=hi*4+r -> q-row
  hlf* pc = part + (size_t)c * ((size_t)S_ * D_);
#pragma unroll
  for (int dt = 0; dt < 8; ++dt)
#pragma unroll
    for (int r = 0; r < 4; ++r)
      pc[(size_t)(i0 + wv * 16 + hi * 4 + r) * D_ + h * HD_ + dt * 16 + l15] =
          (hlf)yacc[dt][r];
}

// ---------------------------------------------------------------------------
// ln_gate: y = sum of partials -> LayerNorm -> * g -> a16.
// ---------------------------------------------------------------------------
__global__ __launch_bounds__(256) void ln_gate(const hlf* __restrict__ part,
                                               const hlf* __restrict__ g,
                                               const void* __restrict__ lnw,
                                               const void* __restrict__ lnb,
                                               hlf* __restrict__ a) {
  const int row = blockIdx.x;
  const int nch = ((row >> 6) + 8) >> 3;   // ceil((bx+1)/8)
  const int t = threadIdx.x;
  const bool lF = is_f32(lnw);

  float v[8], s = 0.f, s2 = 0.f;
#pragma unroll
  for (int e = 0; e < 8; ++e) {
    int col = t + 256 * e;
    size_t off = (size_t)row * D_ + col;
    float y = 0.f;
    for (int cc = 0; cc < nch; ++cc)
      y += (float)part[(size_t)cc * ((size_t)S_ * D_) + off];
    v[e] = y;
    s += y;
    s2 += y * y;
  }
#pragma unroll
  for (int off = 32; off > 0; off >>= 1) {
    s += __shfl_down(s, off);
    s2 += __shfl_down(s2, off);
  }
  __shared__ float red[8];
  __shared__ float mv[2];
  if ((t & 63) == 0) { red[(t >> 6) * 2] = s; red[(t >> 6) * 2 + 1] = s2; }
  __syncthreads();
  if (t == 0) {
    float S1 = red[0] + red[2] + red[4] + red[6];
    float S2 = red[1] + red[3] + red[5] + red[7];
    float mu = S1 * (1.f / (float)D_);
    float var = S2 * (1.f / (float)D_) - mu * mu;
    mv[0] = mu;
    mv[1] = rsqrtf(var + 1e-5f);
  }
  __syncthreads();
  float mu = mv[0], rstd = mv[1];
#pragma unroll
  for (int e = 0; e < 8; ++e) {
    int col = t + 256 * e;
    float lw = lF ? ((const float*)lnw)[col] : (float)((const __bf16*)lnw)[col];
    float lb = lF ? ((const float*)lnb)[col] : (float)((const __bf16*)lnb)[col];
    float val = (v[e] - mu) * rstd * lw + lb;
    float gg = (float)g[(size_t)row * D_ + col];
    a[(size_t)row * D_ + col] = (hlf)(val * gg);
  }
}

// ---------------------------------------------------------------------------
__global__ __launch_bounds__(256) void addk4(
    const hlf* __restrict__ p0, const hlf* __restrict__ p1,
    const hlf* __restrict__ p2, const hlf* __restrict__ p3,
    float* __restrict__ o) {
  size_t i = ((size_t)blockIdx.x * 256 + threadIdx.x) * 8;
  hlf8 a = *(const hlf8*)(p0 + i);
  hlf8 b = *(const hlf8*)(p1 + i);
  hlf8 cc = *(const hlf8*)(p2 + i);
  hlf8 d = *(const hlf8*)(p3 + i);
  f32x4 r0, r1;
#pragma unroll
  for (int e = 0; e < 4; ++e) {
    r0[e] = (float)a[e] + (float)b[e] + (float)cc[e] + (float)d[e];
    r1[e] = (float)a[e + 4] + (float)b[e + 4] + (float)cc[e + 4] + (float)d[e + 4];
  }
  *(f32x4*)(o + i) = r0;
  *(f32x4*)(o + i + 4) = r1;
}

// ---------------------------------------------------------------------------
extern "C" void kernel_launch(void* const* d_in, const int* in_sizes, int n_in,
                              void* d_out, int out_size, void* d_ws, size_t ws_size,
                              hipStream_t stream) {
  const float* x   = (const float*)d_in[0];
  const float* wq  = (const float*)d_in[1];
  const float* wk  = (const float*)d_in[2];
  const float* wv  = (const float*)d_in[3];
  const float* wg  = (const float*)d_in[4];
  const float* wo  = (const float*)d_in[5];
  const void* lnw = d_in[6];
  const void* lnb = d_in[7];

  char* ws = (char*)d_ws;
  hlf* x16  = (hlf*)(ws);                    // 8M; -> part0 after QKVG
  hlf* wq16 = (hlf*)(ws + (8ull  << 20));    // -> part1
  hlf* wk16 = (hlf*)(ws + (16ull << 20));    // -> part2
  hlf* wv16 = (hlf*)(ws + (24ull << 20));    // -> part3
  hlf* wg16 = (hlf*)(ws + (32ull << 20));
  hlf* wo16 = (hlf*)(ws + (40ull << 20));
  hlf* q16  = (hlf*)(ws + (48ull << 20));    // -> wo partial 0
  hlf* k16  = (hlf*)(ws + (56ull << 20));    // -> wo partial 1
  hlf* vt   = (hlf*)(ws + (64ull << 20));    // -> wo partial 2
  hlf* wp3  = (hlf*)(ws + (72ull << 20));    // wo partial 3 (old p0 slot)
  hlf* a16  = (hlf*)(ws + (88ull << 20));
  hlf* part = x16;                           // 4 x 8M fp16 attn partials
  hlf* g    = (hlf*)d_out;                   // dead before addk4 overwrite
  float* out = (float*)d_out;

  dim3 blk(256);
  cvt16<<<dim3(1024, 6), blk, 0, stream>>>(
      x, wq, wk, wv, wg, wo, x16, wq16, wk16, wv16, wg16, wo16);
  // QKVG fused: nibbles z0..z3 = 1(q fp16), 1(k fp16), 3(vT), 5(g silu)
  gemm16<<<dim3(16, 16, 4), blk, 0, stream>>>(
      x16, wq16, wk16, wv16, wg16, q16, k16, vt, g, 0x5311, 0, 64);
  attn_part<<<dim3(80, 16), blk, 0, stream>>>(q16, k16, vt, part);
  ln_gate<<<dim3(2048), blk, 0, stream>>>(part, g, lnw, lnb, a16);
  // wo split-K=4: z = K-quarter, fp16 partials into dead q16/k16/vt/wp3
  gemm16<<<dim3(16, 16, 4), blk, 0, stream>>>(
      a16, wo16, wo16, wo16, wo16, q16, k16, vt, wp3, 0x1111, 512, 16);
  addk4<<<dim3(2048), blk, 0, stream>>>(q16, k16, vt, wp3, out);
}